// Round 9
// baseline (42.243 us; speedup 1.0000x reference)
//
#include <hip/hip_runtime.h>

#define B_ 32
#define N_ 4096
#define M_ 32
#define F_ 256
#define A_ 8

typedef float f32x4 __attribute__((ext_vector_type(4)));
typedef int   i32x4 __attribute__((ext_vector_type(4)));

// workspace layout (floats):
//   [0, B*A*F)            anchor_feat (B,A,F)                 = 65536
//   [WS_E2, +B*A)         e2 = anchor_feat @ (a1-a2)          = 256
//   [WS_ATTN, +B*N*A)     normalized attn weights (B,N,A)     = 1048576
#define WS_AF 0
#define WS_E2 (B_ * A_ * F_)
#define WS_ATTN (WS_E2 + B_ * A_)
#define WS_FLOATS_NEEDED (WS_ATTN + B_ * N_ * A_)

// ---- kernel 1: anchor_feat[b,k,:] = fatoms[b, idx[b,k], :] @ W ; e2 ----
// e1 = h@(a1+a2) is provably irrelevant: e[b,n,k] = e1[b,n] + e2[b,k] and
// softmax over k is invariant to the per-row constant e1 (masked entries are
// -1e9 absolute; exp underflows to 0 either way; all-masked -> uniform 1/8).
__global__ __launch_bounds__(256) void anchor_kernel(const float* __restrict__ fatoms,
                                                     const int* __restrict__ anchor_idx,
                                                     const float* __restrict__ W,
                                                     const float* __restrict__ a,
                                                     float* __restrict__ ws) {
    int bk = blockIdx.x;  // b*A_ + k
    int b  = bk / A_;
    int f  = threadIdx.x;
    __shared__ float xs[F_];
    __shared__ float red[F_];
    int idx = anchor_idx[bk];
    xs[f] = fatoms[((size_t)b * N_ + idx) * F_ + f];
    __syncthreads();
    float acc[4] = {0.f, 0.f, 0.f, 0.f};
    for (int i0 = 0; i0 < F_; i0 += 16) {
#pragma unroll
        for (int j = 0; j < 16; ++j)
            acc[j & 3] += xs[i0 + j] * W[(i0 + j) * F_ + f];  // coalesced over f
    }
    float accs = (acc[0] + acc[1]) + (acc[2] + acc[3]);
    ws[WS_AF + bk * F_ + f] = accs;
    red[f] = accs * (a[f] - a[f + F_]);
    __syncthreads();
    for (int s = 128; s > 0; s >>= 1) {
        if (f < s) red[f] += red[f + s];
        __syncthreads();
    }
    if (f == 0) ws[WS_E2 + bk] = red[0];
}

// ---- kernel A: attn weights only (reads agraph, writes 32B/row) --------
__global__ __launch_bounds__(64) void attn_kernel(const int* __restrict__ agraph,
                                                  const int* __restrict__ anchor_idx,
                                                  const float* __restrict__ ws,
                                                  float* __restrict__ attn) {
    int lane = threadIdx.x;
    const int chunks_per_batch = N_ / 64;
    int b    = blockIdx.x / chunks_per_batch;
    int row  = (blockIdx.x % chunks_per_batch) * 64 + lane;

    const i32x4* gp = (const i32x4*)(agraph + ((size_t)b * N_ + row) * M_);
    i32x4 g[M_ / 4];
#pragma unroll
    for (int j = 0; j < M_ / 4; ++j) g[j] = gp[j];

    int   anch[A_];
    float e2r[A_];
#pragma unroll
    for (int k = 0; k < A_; ++k) {
        anch[k] = anchor_idx[b * A_ + k];
        e2r[k]  = ws[WS_E2 + b * A_ + k];
    }
    float m8 = e2r[0];
#pragma unroll
    for (int k = 1; k < A_; ++k) m8 = fmaxf(m8, e2r[k]);
    float E[A_];
#pragma unroll
    for (int k = 0; k < A_; ++k) E[k] = __expf(e2r[k] - m8);

    unsigned mk = 0;
#pragma unroll
    for (int j = 0; j < M_ / 4; ++j) {
#pragma unroll
        for (int k = 0; k < A_; ++k) {
            int hit = (g[j].x == anch[k]) | (g[j].y == anch[k]) |
                      (g[j].z == anch[k]) | (g[j].w == anch[k]);
            mk |= hit ? (1u << k) : 0u;
        }
    }
    float p[A_], s = 0.f;
#pragma unroll
    for (int k = 0; k < A_; ++k) { p[k] = (mk & (1u << k)) ? E[k] : 0.f; s += p[k]; }
    if (mk == 0) {
#pragma unroll
        for (int k = 0; k < A_; ++k) p[k] = 1.f;
        s = 8.f;
    }
    float rinv = __builtin_amdgcn_rcpf(s);
    f32x4 pa = {p[0] * rinv, p[1] * rinv, p[2] * rinv, p[3] * rinv};
    f32x4 pb = {p[4] * rinv, p[5] * rinv, p[6] * rinv, p[7] * rinv};
    f32x4* ap = (f32x4*)(attn + ((size_t)b * N_ + row) * A_);
    ap[0] = pa;
    ap[1] = pb;
}

// ---- kernel B: pure-write mix kernel (fill-kernel-like store stream) ---
#define RPW 64

__global__ __launch_bounds__(64) void store_kernel(const float* __restrict__ ws,
                                                   const float* __restrict__ attn,
                                                   float* __restrict__ out) {
    int lane = threadIdx.x;
    const int chunks_per_batch = N_ / RPW;  // 64
    int b    = blockIdx.x / chunks_per_batch;
    int row0 = (blockIdx.x % chunks_per_batch) * RPW;

    const float* af = ws + WS_AF + b * (A_ * F_);
    f32x4 afr[A_];
#pragma unroll
    for (int k = 0; k < A_; ++k) afr[k] = *(const f32x4*)(af + k * F_ + lane * 4);

    // attn rows for this chunk: wave-uniform addresses -> scalar loads
    const float* ab = attn + ((size_t)b * N_ + row0) * A_;
    size_t base = ((size_t)b * N_ + row0) * F_ + lane * 4;
    for (int r0 = 0; r0 < RPW; r0 += 4) {
        f32x4 o[4];
#pragma unroll
        for (int u = 0; u < 4; ++u) {
            const float* pr = ab + (size_t)(r0 + u) * A_;
            f32x4 pa = *(const f32x4*)pr;       // uniform -> s_load
            f32x4 pb = *(const f32x4*)(pr + 4);
            f32x4 t = pa.x * afr[0];
            t += pa.y * afr[1];
            t += pa.z * afr[2];
            t += pa.w * afr[3];
            t += pb.x * afr[4];
            t += pb.y * afr[5];
            t += pb.z * afr[6];
            t += pb.w * afr[7];
            o[u] = t;
        }
#pragma unroll
        for (int u = 0; u < 4; ++u)
            *(f32x4*)(out + base + (size_t)(r0 + u) * F_) = o[u];
    }
}

// ---- fallback: fused main (R8) if ws can't hold the attn buffer --------
__global__ __launch_bounds__(64) void fused_kernel(const int* __restrict__ agraph,
                                                   const int* __restrict__ anchor_idx,
                                                   const float* __restrict__ ws,
                                                   float* __restrict__ out) {
    int lane = threadIdx.x;
    const int chunks_per_batch = N_ / RPW;
    int b    = blockIdx.x / chunks_per_batch;
    int row0 = (blockIdx.x % chunks_per_batch) * RPW;

    const i32x4* gp = (const i32x4*)(agraph + ((size_t)b * N_ + row0 + lane) * M_);
    i32x4 g[M_ / 4];
#pragma unroll
    for (int j = 0; j < M_ / 4; ++j) g[j] = gp[j];

    const float* af = ws + WS_AF + b * (A_ * F_);
    __shared__ float attn_s[RPW][A_];
    int   anch[A_];
    float e2r[A_];
#pragma unroll
    for (int k = 0; k < A_; ++k) {
        anch[k] = anchor_idx[b * A_ + k];
        e2r[k]  = ws[WS_E2 + b * A_ + k];
    }
    float m8 = e2r[0];
#pragma unroll
    for (int k = 1; k < A_; ++k) m8 = fmaxf(m8, e2r[k]);
    float E[A_];
#pragma unroll
    for (int k = 0; k < A_; ++k) E[k] = __expf(e2r[k] - m8);
    f32x4 afr[A_];
#pragma unroll
    for (int k = 0; k < A_; ++k) afr[k] = *(const f32x4*)(af + k * F_ + lane * 4);
    {
        unsigned mk = 0;
#pragma unroll
        for (int j = 0; j < M_ / 4; ++j) {
#pragma unroll
            for (int k = 0; k < A_; ++k) {
                int hit = (g[j].x == anch[k]) | (g[j].y == anch[k]) |
                          (g[j].z == anch[k]) | (g[j].w == anch[k]);
                mk |= hit ? (1u << k) : 0u;
            }
        }
        float p[A_], s = 0.f;
#pragma unroll
        for (int k = 0; k < A_; ++k) { p[k] = (mk & (1u << k)) ? E[k] : 0.f; s += p[k]; }
        if (mk == 0) {
#pragma unroll
            for (int k = 0; k < A_; ++k) p[k] = 1.f;
            s = 8.f;
        }
        float rinv = __builtin_amdgcn_rcpf(s);
#pragma unroll
        for (int k = 0; k < A_; ++k) attn_s[lane][k] = p[k] * rinv;
    }
    __syncthreads();
    size_t base = ((size_t)b * N_ + row0) * F_ + lane * 4;
    for (int r0 = 0; r0 < RPW; r0 += 4) {
        f32x4 o[4];
#pragma unroll
        for (int u = 0; u < 4; ++u) {
            f32x4 pa = *(const f32x4*)&attn_s[r0 + u][0];
            f32x4 pb = *(const f32x4*)&attn_s[r0 + u][4];
            f32x4 t = pa.x * afr[0];
            t += pa.y * afr[1];
            t += pa.z * afr[2];
            t += pa.w * afr[3];
            t += pb.x * afr[4];
            t += pb.y * afr[5];
            t += pb.z * afr[6];
            t += pb.w * afr[7];
            o[u] = t;
        }
#pragma unroll
        for (int u = 0; u < 4; ++u)
            *(f32x4*)(out + base + (size_t)(r0 + u) * F_) = o[u];
    }
}

extern "C" void kernel_launch(void* const* d_in, const int* in_sizes, int n_in,
                              void* d_out, int out_size, void* d_ws, size_t ws_size,
                              hipStream_t stream) {
    const float* fatoms     = (const float*)d_in[0];
    const int*   agraph     = (const int*)d_in[1];
    const int*   anchor_idx = (const int*)d_in[2];
    const float* W          = (const float*)d_in[3];
    const float* a          = (const float*)d_in[4];
    float*       out        = (float*)d_out;
    float*       ws         = (float*)d_ws;

    hipLaunchKernelGGL(anchor_kernel, dim3(B_ * A_), dim3(256), 0, stream,
                       fatoms, anchor_idx, W, a, ws);

    if (ws_size >= (size_t)WS_FLOATS_NEEDED * sizeof(float)) {
        float* attn = ws + WS_ATTN;
        hipLaunchKernelGGL(attn_kernel, dim3(B_ * (N_ / 64)), dim3(64), 0, stream,
                           agraph, anchor_idx, ws, attn);
        hipLaunchKernelGGL(store_kernel, dim3(B_ * (N_ / RPW)), dim3(64), 0, stream,
                           ws, attn, out);
    } else {
        hipLaunchKernelGGL(fused_kernel, dim3(B_ * (N_ / RPW)), dim3(64), 0, stream,
                           agraph, anchor_idx, ws, out);
    }
}